// Round 3
// baseline (376.071 us; speedup 1.0000x reference)
//
#include <hip/hip_runtime.h>
#include <cstdint>

#define NANCHOR 33600
#define BATCH   8
#define MGT     32
#define NCLS    80

// ---------------------------------------------------------------------------
// Anchor geometry: levels are [160x160 stride 8 | 80x80 stride 16 | 40x40 stride 32]
// p layout per level: [B, 144, H, W]; channel stride = H*W; anchor n = y*W + x.
// ---------------------------------------------------------------------------
struct AInfo {
    const float* ch0;   // &p_level[b][0][n]  (add c*hw for channel c)
    int   hw;
    float apx, apy, st;
};

__device__ __forceinline__ AInfo anchor_info(const float* p0, const float* p1,
                                             const float* p2, int b, int n) {
    AInfo r;
    if (n < 25600) {
        int nn = n;
        r.ch0 = p0 + (size_t)b * (144 * 25600) + nn;
        r.hw = 25600; r.st = 8.f;
        r.apx = (float)(nn % 160) + 0.5f;
        r.apy = (float)(nn / 160) + 0.5f;
    } else if (n < 32000) {
        int nn = n - 25600;
        r.ch0 = p1 + (size_t)b * (144 * 6400) + nn;
        r.hw = 6400; r.st = 16.f;
        r.apx = (float)(nn % 80) + 0.5f;
        r.apy = (float)(nn / 80) + 0.5f;
    } else {
        int nn = n - 32000;
        r.ch0 = p2 + (size_t)b * (144 * 1600) + nn;
        r.hw = 1600; r.st = 32.f;
        r.apx = (float)(nn % 40) + 0.5f;
        r.apy = (float)(nn / 40) + 0.5f;
    }
    return r;
}

__device__ __forceinline__ float ciou_f(float b1x1, float b1y1, float b1x2, float b1y2,
                                        float g1x, float g1y, float g2x, float g2y) {
    const float eps = 1e-7f;
    float w1 = b1x2 - b1x1, h1 = b1y2 - b1y1;
    float w2 = g2x - g1x,   h2 = g2y - g1y;
    float iw = fminf(b1x2, g2x) - fmaxf(b1x1, g1x);
    float ih = fminf(b1y2, g2y) - fmaxf(b1y1, g1y);
    float inter = fmaxf(iw, 0.f) * fmaxf(ih, 0.f);
    float uni = w1 * h1 + w2 * h2 - inter + eps;
    float iou = inter / uni;
    float cw = fmaxf(b1x2, g2x) - fminf(b1x1, g1x);
    float ch = fmaxf(b1y2, g2y) - fminf(b1y1, g1y);
    float c2 = cw * cw + ch * ch + eps;
    float dx = g1x + g2x - b1x1 - b1x2;
    float dy = g1y + g2y - b1y1 - b1y2;
    float rho2 = (dx * dx + dy * dy) * 0.25f;
    float t = atanf(w2 / (h2 + eps)) - atanf(w1 / (h1 + eps));
    float v = 0.40528473456935108577f * t * t;          // 4/pi^2
    float alpha = v / (v - iou + (1.f + eps));
    return iou - (rho2 / c2 + v * alpha);
}

__device__ __forceinline__ float4 max4(float4 a, float4 b) {
    return make_float4(fmaxf(a.x, b.x), fmaxf(a.y, b.y), fmaxf(a.z, b.z), fmaxf(a.w, b.w));
}
__device__ __forceinline__ float fast_splus(float x) {
    // softplus = max(x,0) + log(1 + e^{-|x|}) via native v_exp/v_log
    return fmaxf(x, 0.f) + __logf(1.f + __expf(-fabsf(x)));
}

// ---------------------------------------------------------------------------
// ws layout:
//   best : unsigned long long [B*N]   packed (score_bits<<32)|(31-m); 0 == no fg
//   pb   : float4 [B*N]               decoded pred boxes (image units, xyxy)
//   acc  : float [128]   per image b: [b*8+0]=softplus_sum, +1=box, +2=dfl,
//                        +3=clspos, +4=numfg; acc[64] = block-completion counter
// ---------------------------------------------------------------------------

__global__ void k_init(float* acc) {
    acc[threadIdx.x] = 0.f;     // 128 threads clear 128 floats (incl. counter)
}

// grid (66, BATCH, 4), block 128. One thread = 4 consecutive anchors.
// role 0: DFL sides 0,1 -> writes {x1,y1} float2 halves of pb, clears best
// role 1: DFL sides 2,3 -> writes {x2,y2}
// role 2: softplus channels 64..103 ; role 3: channels 104..143
__global__ __launch_bounds__(128) void k_decode(const float* __restrict__ p0,
                                                const float* __restrict__ p1,
                                                const float* __restrict__ p2,
                                                float2* __restrict__ pb2,
                                                unsigned long long* __restrict__ best,
                                                float* __restrict__ acc) {
    int b = blockIdx.y;
    int role = blockIdx.z;
    int t = blockIdx.x * 128 + threadIdx.x;   // anchor-group index in image

    if (role >= 2) {
        float sp = 0.f;
        if (t < NANCHOR / 4) {
            int n = t * 4;
            const float* ch0; int hw;
            if (n < 25600)      { ch0 = p0 + (size_t)b * (144 * 25600) + n;          hw = 25600; }
            else if (n < 32000) { ch0 = p1 + (size_t)b * (144 * 6400) + (n - 25600); hw = 6400; }
            else                { ch0 = p2 + (size_t)b * (144 * 1600) + (n - 32000); hw = 1600; }
            int c0 = 64 + (role - 2) * 40;
#pragma unroll 8
            for (int c = 0; c < 40; c++) {
                float4 x = *(const float4*)(ch0 + (size_t)(c0 + c) * hw);
                sp += fast_splus(x.x) + fast_splus(x.y) + fast_splus(x.z) + fast_splus(x.w);
            }
        }
#pragma unroll
        for (int o = 32; o > 0; o >>= 1) sp += __shfl_down(sp, o, 64);
        if ((threadIdx.x & 63) == 0) atomicAdd(&acc[b * 8 + 0], sp);
        return;
    }

    if (t >= NANCHOR / 4) return;
    int n = t * 4;
    const float* ch0; int hw; float st, apx, apy;
    if (n < 25600) {
        ch0 = p0 + (size_t)b * (144 * 25600) + n;
        hw = 25600; st = 8.f;
        apx = (float)(n % 160) + 0.5f; apy = (float)(n / 160) + 0.5f;
    } else if (n < 32000) {
        int nn = n - 25600;
        ch0 = p1 + (size_t)b * (144 * 6400) + nn;
        hw = 6400; st = 16.f;
        apx = (float)(nn % 80) + 0.5f; apy = (float)(nn / 80) + 0.5f;
    } else {
        int nn = n - 32000;
        ch0 = p2 + (size_t)b * (144 * 1600) + nn;
        hw = 1600; st = 32.f;
        apx = (float)(nn % 40) + 0.5f; apy = (float)(nn / 40) + 0.5f;
    }

    int k0 = role * 2;                  // sides {0,1} or {2,3}
    float d[2][4];
#pragma unroll
    for (int kk = 0; kk < 2; kk++) {
        float4 v[16];
#pragma unroll
        for (int r = 0; r < 16; r++)
            v[r] = *(const float4*)(ch0 + (size_t)((k0 + kk) * 16 + r) * hw);
        float4 mx = v[0];
#pragma unroll
        for (int r = 1; r < 16; r++) mx = max4(mx, v[r]);
        float4 s  = make_float4(0.f, 0.f, 0.f, 0.f);
        float4 sw = make_float4(0.f, 0.f, 0.f, 0.f);
#pragma unroll
        for (int r = 0; r < 16; r++) {
            float fr = (float)r;
            float ex = __expf(v[r].x - mx.x);
            float ey = __expf(v[r].y - mx.y);
            float ez = __expf(v[r].z - mx.z);
            float ew = __expf(v[r].w - mx.w);
            s.x += ex; s.y += ey; s.z += ez; s.w += ew;
            sw.x += ex * fr; sw.y += ey * fr; sw.z += ez * fr; sw.w += ew * fr;
        }
        d[kk][0] = sw.x / s.x; d[kk][1] = sw.y / s.y;
        d[kk][2] = sw.z / s.z; d[kk][3] = sw.w / s.w;
    }

    size_t base = (size_t)b * NANCHOR + n;
    if (role == 0) {
#pragma unroll
        for (int i = 0; i < 4; i++) {
            float ax = apx + (float)i;
            pb2[(base + i) * 2 + 0] = make_float2((ax - d[0][i]) * st, (apy - d[1][i]) * st);
        }
        // clear fg table for k_assign (runs strictly after this kernel)
#pragma unroll
        for (int i = 0; i < 4; i++) best[base + i] = 0ull;
    } else {
#pragma unroll
        for (int i = 0; i < 4; i++) {
            float ax = apx + (float)i;
            pb2[(base + i) * 2 + 1] = make_float2((ax + d[0][i]) * st, (apy + d[1][i]) * st);
        }
    }
}

__global__ __launch_bounds__(256) void k_assign(const float* __restrict__ p0,
                                                const float* __restrict__ p1,
                                                const float* __restrict__ p2,
                                                const float4* __restrict__ pb,
                                                const float* __restrict__ gtb,
                                                const int* __restrict__ gtl,
                                                unsigned long long* __restrict__ best) {
    int bm = blockIdx.x;          // 256 blocks: one per (b, m)
    int b = bm >> 5, m = bm & 31;
    const float* g = gtb + (size_t)(b * MGT + m) * 4;
    float g0 = g[0], g1 = g[1], g2 = g[2], g3 = g[3];
    int label = gtl[b * MGT + m];
    int tid = threadIdx.x;

    float tv[10];
    int   ti[10];
#pragma unroll
    for (int j = 0; j < 10; j++) { tv[j] = -1.f; ti[j] = 0x7fffffff; }
    float maxu = 0.f;   // max over UNMASKED align (pre iou>0.1 filter)

    for (int n = tid; n < NANCHOR; n += 256) {
        AInfo ai = anchor_info(p0, p1, p2, b, n);
        float ax = ai.apx * ai.st, ay = ai.apy * ai.st;
        if (ax < g0 || ax > g2 || ay < g1 || ay > g3) continue;   // in_gt == 0 -> align 0
        float4 box = pb[b * NANCHOR + n];
        float c = ciou_f(box.x, box.y, box.z, box.w, g0, g1, g2, g3);
        float iou = fmaxf(c, 0.f);
        if (iou <= 0.f) continue;                                  // align 0
        float pcv = ai.ch0[(size_t)(64 + label) * ai.hw];
        float ps = 1.f / (1.f + __expf(-pcv));
        float i2 = iou * iou;
        float a = ps * i2 * i2 * i2;                               // ps^1 * iou^6
        maxu = fmaxf(maxu, a);
        if (iou > 0.1f && a > tv[9]) {
            // insert; strict > keeps earlier (lower n) ahead on ties == top_k stability
            tv[9] = a; ti[9] = n;
#pragma unroll
            for (int j = 9; j > 0; --j) {
                if (tv[j] > tv[j - 1]) {
                    float tf = tv[j]; tv[j] = tv[j - 1]; tv[j - 1] = tf;
                    int   tt = ti[j]; ti[j] = ti[j - 1]; ti[j - 1] = tt;
                }
            }
        }
    }

    __shared__ float sval[2560];
    __shared__ int   sidx[2560];
    __shared__ float rv[256];
    __shared__ int   ra[256];
    __shared__ int   rs[256];
    __shared__ float smax[256];

#pragma unroll
    for (int j = 0; j < 10; j++) {
        sval[tid * 10 + j] = tv[j];
        sidx[tid * 10 + j] = ti[j];
    }
    smax[tid] = maxu;
    __syncthreads();
    for (int s = 128; s > 0; s >>= 1) {
        if (tid < s) smax[tid] = fmaxf(smax[tid], smax[tid + s]);
        __syncthreads();
    }
    float denom = smax[0] + 1e-9f;

    // 10 rounds of block argmax (value desc, anchor idx asc) over 2560 candidates
    for (int r = 0; r < 10; r++) {
        float bv = -1.f; int ba = 0x7fffffff; int bs = -1;
#pragma unroll
        for (int j = 0; j < 10; j++) {
            int s0 = tid * 10 + j;
            float v = sval[s0]; int a0 = sidx[s0];
            if (v > bv || (v == bv && a0 < ba)) { bv = v; ba = a0; bs = s0; }
        }
        rv[tid] = bv; ra[tid] = ba; rs[tid] = bs;
        __syncthreads();
        for (int s = 128; s > 0; s >>= 1) {
            if (tid < s) {
                if (rv[tid + s] > rv[tid] ||
                    (rv[tid + s] == rv[tid] && ra[tid + s] < ra[tid])) {
                    rv[tid] = rv[tid + s]; ra[tid] = ra[tid + s]; rs[tid] = rs[tid + s];
                }
            }
            __syncthreads();
        }
        if (tid == 0 && rv[0] > 0.f) {
            float nv = rv[0] / denom;                 // normalized score in (0, 1]
            unsigned long long pk =
                ((unsigned long long)__float_as_uint(nv) << 32) |
                (unsigned long long)(31 - m);         // ties -> lower m wins (argmax-first)
            atomicMax(&best[(size_t)b * NANCHOR + ra[0]], pk);
            sval[rs[0]] = -1.f;
        }
        __syncthreads();
    }
}

// k_final also folds the per-image combine: last block (fence+counter) writes out[0].
__global__ __launch_bounds__(256) void k_final(const float* __restrict__ p0,
                                               const float* __restrict__ p1,
                                               const float* __restrict__ p2,
                                               const float4* __restrict__ pb,
                                               const float* __restrict__ gtb,
                                               const int* __restrict__ gtl,
                                               const unsigned long long* __restrict__ best,
                                               float* __restrict__ acc,
                                               float* __restrict__ out) {
    int tid = blockIdx.x * blockDim.x + threadIdx.x;
    int b = tid / NANCHOR, n = tid % NANCHOR;
    unsigned long long pk = best[tid];
    unsigned int hi = (unsigned int)(pk >> 32);
    if (hi != 0u) {
        float score = __uint_as_float(hi);
        int m = 31 - (int)(pk & 0xffffffffull);
        const float* g = gtb + (size_t)(b * MGT + m) * 4;
        float g0 = g[0], g1 = g[1], g2 = g[2], g3 = g[3];
        int label = gtl[b * MGT + m];
        float4 box = pb[tid];
        float c = ciou_f(box.x, box.y, box.z, box.w, g0, g1, g2, g3);

        AInfo ai = anchor_info(p0, p1, p2, b, n);
        float inv_st = 1.f / ai.st;           // exact (power of two)
        float t4[4] = { ai.apx - g0 * inv_st, ai.apy - g1 * inv_st,
                        g2 * inv_st - ai.apx, g3 * inv_st - ai.apy };
        float dfl = 0.f;
#pragma unroll
        for (int k = 0; k < 4; k++) {
            float t = fminf(fmaxf(t4[k], 0.f), 14.99f);   // box2dist clamp
            int left = (int)floorf(t);
            int right = (left + 1 < 15) ? left + 1 : 15;
            float wl = (float)right - t;
            float wr = t - (float)left;
            float v[16];
            float mx = -1e30f;
#pragma unroll
            for (int r = 0; r < 16; r++) {
                v[r] = ai.ch0[(size_t)(k * 16 + r) * ai.hw];
                mx = fmaxf(mx, v[r]);
            }
            float s = 0.f;
#pragma unroll
            for (int r = 0; r < 16; r++) s += expf(v[r] - mx);
            float lse = mx + logf(s);
            dfl += (lse - v[left]) * wl + (lse - v[right]) * wr;
        }
        float pcv = ai.ch0[(size_t)(64 + label) * ai.hw];

        atomicAdd(&acc[b * 8 + 1], 1.f - c);       // box: (1 - ciou)
        atomicAdd(&acc[b * 8 + 2], dfl);           // dfl: sum over 4 sides
        atomicAdd(&acc[b * 8 + 3], pcv * score);   // cls positive term
        atomicAdd(&acc[b * 8 + 4], 1.f);           // num_fg
    }

    // ---- last-block combine ----
    __threadfence();          // make this thread's atomics visible device-wide
    __syncthreads();
    if (threadIdx.x == 0) {
        unsigned int old = atomicAdd((unsigned int*)(acc + 64), 1u);
        if (old == (unsigned int)(gridDim.x - 1)) {
            __threadfence();  // acquire: all other blocks' atomics now visible
            float total = 0.f;
            for (int bb = 0; bb < BATCH; bb++) {
                float nfr = acc[bb * 8 + 4];
                float has = nfr > 0.f ? 1.f : 0.f;
                float nf = fmaxf(nfr, 1.f);
                float box_l = acc[bb * 8 + 1] / nf;
                float cls_l = (acc[bb * 8 + 0] - acc[bb * 8 + 3]) / (float)NANCHOR;
                float dfl_l = acc[bb * 8 + 2] / (nf * 4.f);
                total += has * (7.5f * box_l + 0.5f * cls_l + 1.5f * dfl_l);
            }
            out[0] = total;
        }
    }
}

extern "C" void kernel_launch(void* const* d_in, const int* in_sizes, int n_in,
                              void* d_out, int out_size, void* d_ws, size_t ws_size,
                              hipStream_t stream) {
    (void)in_sizes; (void)n_in; (void)out_size; (void)ws_size;
    const float* p0  = (const float*)d_in[0];
    const float* p1  = (const float*)d_in[1];
    const float* p2  = (const float*)d_in[2];
    const float* gtb = (const float*)d_in[3];
    const int*   gtl = (const int*)d_in[4];
    // d_in[5] = strides (8,16,32) — hardcoded in anchor_info

    char* ws = (char*)d_ws;
    unsigned long long* best = (unsigned long long*)ws;                       // 2.15 MB
    float4* pb = (float4*)(ws + (size_t)BATCH * NANCHOR * 8);                 // 4.30 MB
    float*  acc = (float*)(ws + (size_t)BATCH * NANCHOR * 8
                              + (size_t)BATCH * NANCHOR * 16);                // 512 B

    const int BN = BATCH * NANCHOR;   // 268800
    k_init   <<<1, 128, 0, stream>>>(acc);
    k_decode <<<dim3(66, BATCH, 4), 128, 0, stream>>>(p0, p1, p2, (float2*)pb, best, acc);
    k_assign <<<BATCH * MGT, 256, 0, stream>>>(p0, p1, p2, pb, gtb, gtl, best);
    k_final  <<<BN / 256, 256, 0, stream>>>(p0, p1, p2, pb, gtb, gtl, best, acc, (float*)d_out);
}

// Round 4
// 318.862 us; speedup vs baseline: 1.1794x; 1.1794x over previous
//
#include <hip/hip_runtime.h>
#include <cstdint>

#define NANCHOR 33600
#define BATCH   8
#define MGT     32
#define NCLS    80

// ---------------------------------------------------------------------------
// Anchor geometry: levels are [160x160 stride 8 | 80x80 stride 16 | 40x40 stride 32]
// p layout per level: [B, 144, H, W]; channel stride = H*W; anchor n = y*W + x.
// ---------------------------------------------------------------------------
struct AInfo {
    const float* ch0;   // &p_level[b][0][n]  (add c*hw for channel c)
    int   hw;
    float apx, apy, st;
};

__device__ __forceinline__ AInfo anchor_info(const float* p0, const float* p1,
                                             const float* p2, int b, int n) {
    AInfo r;
    if (n < 25600) {
        int nn = n;
        r.ch0 = p0 + (size_t)b * (144 * 25600) + nn;
        r.hw = 25600; r.st = 8.f;
        r.apx = (float)(nn % 160) + 0.5f;
        r.apy = (float)(nn / 160) + 0.5f;
    } else if (n < 32000) {
        int nn = n - 25600;
        r.ch0 = p1 + (size_t)b * (144 * 6400) + nn;
        r.hw = 6400; r.st = 16.f;
        r.apx = (float)(nn % 80) + 0.5f;
        r.apy = (float)(nn / 80) + 0.5f;
    } else {
        int nn = n - 32000;
        r.ch0 = p2 + (size_t)b * (144 * 1600) + nn;
        r.hw = 1600; r.st = 32.f;
        r.apx = (float)(nn % 40) + 0.5f;
        r.apy = (float)(nn / 40) + 0.5f;
    }
    return r;
}

__device__ __forceinline__ float ciou_f(float b1x1, float b1y1, float b1x2, float b1y2,
                                        float g1x, float g1y, float g2x, float g2y) {
    const float eps = 1e-7f;
    float w1 = b1x2 - b1x1, h1 = b1y2 - b1y1;
    float w2 = g2x - g1x,   h2 = g2y - g1y;
    float iw = fminf(b1x2, g2x) - fmaxf(b1x1, g1x);
    float ih = fminf(b1y2, g2y) - fmaxf(b1y1, g1y);
    float inter = fmaxf(iw, 0.f) * fmaxf(ih, 0.f);
    float uni = w1 * h1 + w2 * h2 - inter + eps;
    float iou = inter / uni;
    float cw = fmaxf(b1x2, g2x) - fminf(b1x1, g1x);
    float ch = fmaxf(b1y2, g2y) - fminf(b1y1, g1y);
    float c2 = cw * cw + ch * ch + eps;
    float dx = g1x + g2x - b1x1 - b1x2;
    float dy = g1y + g2y - b1y1 - b1y2;
    float rho2 = (dx * dx + dy * dy) * 0.25f;
    float t = atanf(w2 / (h2 + eps)) - atanf(w1 / (h1 + eps));
    float v = 0.40528473456935108577f * t * t;          // 4/pi^2
    float alpha = v / (v - iou + (1.f + eps));
    return iou - (rho2 / c2 + v * alpha);
}

__device__ __forceinline__ float4 max4(float4 a, float4 b) {
    return make_float4(fmaxf(a.x, b.x), fmaxf(a.y, b.y), fmaxf(a.z, b.z), fmaxf(a.w, b.w));
}
__device__ __forceinline__ float fast_splus(float x) {
    // softplus = max(x,0) + log(1 + e^{-|x|}) via native v_exp/v_log
    return fmaxf(x, 0.f) + __logf(1.f + __expf(-fabsf(x)));
}

// ---------------------------------------------------------------------------
// ws layout:
//   best : unsigned long long [B*N]   packed (score_bits<<32)|(31-m); 0 == no fg
//   pb   : float4 [B*N]               decoded pred boxes (image units, xyxy)
//   acc  : float [128]   per image b: [b*8+0]=softplus_sum, +1=box, +2=dfl,
//                        +3=clspos, +4=numfg
// ---------------------------------------------------------------------------

__global__ void k_init(float* acc) {
    acc[threadIdx.x] = 0.f;     // 128 threads clear 128 floats
}

// grid (66, BATCH, 4), block 128. One thread = 4 consecutive anchors.
// role 0: DFL sides 0,1 -> writes {x1,y1} float2 halves of pb, clears best
// role 1: DFL sides 2,3 -> writes {x2,y2}
// role 2: softplus channels 64..103 ; role 3: channels 104..143
__global__ __launch_bounds__(128) void k_decode(const float* __restrict__ p0,
                                                const float* __restrict__ p1,
                                                const float* __restrict__ p2,
                                                float2* __restrict__ pb2,
                                                unsigned long long* __restrict__ best,
                                                float* __restrict__ acc) {
    int b = blockIdx.y;
    int role = blockIdx.z;
    int t = blockIdx.x * 128 + threadIdx.x;   // anchor-group index in image

    if (role >= 2) {
        float sp = 0.f;
        if (t < NANCHOR / 4) {
            int n = t * 4;
            const float* ch0; int hw;
            if (n < 25600)      { ch0 = p0 + (size_t)b * (144 * 25600) + n;          hw = 25600; }
            else if (n < 32000) { ch0 = p1 + (size_t)b * (144 * 6400) + (n - 25600); hw = 6400; }
            else                { ch0 = p2 + (size_t)b * (144 * 1600) + (n - 32000); hw = 1600; }
            int c0 = 64 + (role - 2) * 40;
#pragma unroll 8
            for (int c = 0; c < 40; c++) {
                float4 x = *(const float4*)(ch0 + (size_t)(c0 + c) * hw);
                sp += fast_splus(x.x) + fast_splus(x.y) + fast_splus(x.z) + fast_splus(x.w);
            }
        }
#pragma unroll
        for (int o = 32; o > 0; o >>= 1) sp += __shfl_down(sp, o, 64);
        if ((threadIdx.x & 63) == 0) atomicAdd(&acc[b * 8 + 0], sp);
        return;
    }

    if (t >= NANCHOR / 4) return;
    int n = t * 4;
    const float* ch0; int hw; float st, apx, apy;
    if (n < 25600) {
        ch0 = p0 + (size_t)b * (144 * 25600) + n;
        hw = 25600; st = 8.f;
        apx = (float)(n % 160) + 0.5f; apy = (float)(n / 160) + 0.5f;
    } else if (n < 32000) {
        int nn = n - 25600;
        ch0 = p1 + (size_t)b * (144 * 6400) + nn;
        hw = 6400; st = 16.f;
        apx = (float)(nn % 80) + 0.5f; apy = (float)(nn / 80) + 0.5f;
    } else {
        int nn = n - 32000;
        ch0 = p2 + (size_t)b * (144 * 1600) + nn;
        hw = 1600; st = 32.f;
        apx = (float)(nn % 40) + 0.5f; apy = (float)(nn / 40) + 0.5f;
    }

    int k0 = role * 2;                  // sides {0,1} or {2,3}
    float d[2][4];
#pragma unroll
    for (int kk = 0; kk < 2; kk++) {
        float4 v[16];
#pragma unroll
        for (int r = 0; r < 16; r++)
            v[r] = *(const float4*)(ch0 + (size_t)((k0 + kk) * 16 + r) * hw);
        float4 mx = v[0];
#pragma unroll
        for (int r = 1; r < 16; r++) mx = max4(mx, v[r]);
        float4 s  = make_float4(0.f, 0.f, 0.f, 0.f);
        float4 sw = make_float4(0.f, 0.f, 0.f, 0.f);
#pragma unroll
        for (int r = 0; r < 16; r++) {
            float fr = (float)r;
            float ex = __expf(v[r].x - mx.x);
            float ey = __expf(v[r].y - mx.y);
            float ez = __expf(v[r].z - mx.z);
            float ew = __expf(v[r].w - mx.w);
            s.x += ex; s.y += ey; s.z += ez; s.w += ew;
            sw.x += ex * fr; sw.y += ey * fr; sw.z += ez * fr; sw.w += ew * fr;
        }
        d[kk][0] = sw.x / s.x; d[kk][1] = sw.y / s.y;
        d[kk][2] = sw.z / s.z; d[kk][3] = sw.w / s.w;
    }

    size_t base = (size_t)b * NANCHOR + n;
    if (role == 0) {
#pragma unroll
        for (int i = 0; i < 4; i++) {
            float ax = apx + (float)i;
            pb2[(base + i) * 2 + 0] = make_float2((ax - d[0][i]) * st, (apy - d[1][i]) * st);
        }
        // clear fg table for k_assign (runs strictly after this kernel)
#pragma unroll
        for (int i = 0; i < 4; i++) best[base + i] = 0ull;
    } else {
#pragma unroll
        for (int i = 0; i < 4; i++) {
            float ax = apx + (float)i;
            pb2[(base + i) * 2 + 1] = make_float2((ax + d[0][i]) * st, (apy + d[1][i]) * st);
        }
    }
}

// One block per (b, m). Scans only the per-level index window covering the GT
// box (conservative ±1; exact float in-gt test inside). Selection semantics
// are order-independent: (align value desc, anchor index asc).
__global__ __launch_bounds__(256) void k_assign(const float* __restrict__ p0,
                                                const float* __restrict__ p1,
                                                const float* __restrict__ p2,
                                                const float4* __restrict__ pb,
                                                const float* __restrict__ gtb,
                                                const int* __restrict__ gtl,
                                                unsigned long long* __restrict__ best) {
    int bm = blockIdx.x;          // 256 blocks: one per (b, m)
    int b = bm >> 5, m = bm & 31;
    const float* g = gtb + (size_t)(b * MGT + m) * 4;
    float g0 = g[0], g1 = g[1], g2 = g[2], g3 = g[3];
    int label = gtl[b * MGT + m];
    int tid = threadIdx.x;

    float tv[10];
    int   ti[10];
#pragma unroll
    for (int j = 0; j < 10; j++) { tv[j] = -1.f; ti[j] = 0x7fffffff; }
    float maxu = 0.f;   // max over UNMASKED align (pre iou>0.1 filter)

    const int   LW[3]   = {160, 80, 40};
    const int   LOFF[3] = {0, 25600, 32000};
    const float LST[3]  = {8.f, 16.f, 32.f};

    for (int l = 0; l < 3; l++) {
        float st = LST[l];
        int W = LW[l];
        float inv_st = 1.f / st;
        int ix0 = max(0,     (int)floorf(g0 * inv_st - 0.5f) - 1);
        int ix1 = min(W - 1, (int)ceilf (g2 * inv_st - 0.5f) + 1);
        int iy0 = max(0,     (int)floorf(g1 * inv_st - 0.5f) - 1);
        int iy1 = min(W - 1, (int)ceilf (g3 * inv_st - 0.5f) + 1);
        int nx = ix1 - ix0 + 1, ny = iy1 - iy0 + 1;
        if (nx <= 0 || ny <= 0) continue;
        int cnt = nx * ny;
        const float* lp = (l == 0) ? p0 : (l == 1) ? p1 : p2;
        int hw = W * W;
        const float* ch0 = lp + (size_t)b * 144 * hw;
        const float* pcls = ch0 + (size_t)(64 + label) * hw;

        for (int idx = tid; idx < cnt; idx += 256) {
            int iy = iy0 + idx / nx;
            int ix = ix0 + idx % nx;
            float ax = ((float)ix + 0.5f) * st;
            float ay = ((float)iy + 0.5f) * st;
            if (ax < g0 || ax > g2 || ay < g1 || ay > g3) continue;   // exact in_gt
            int nn = iy * W + ix;
            int n = LOFF[l] + nn;
            float4 box = pb[(size_t)b * NANCHOR + n];
            float c = ciou_f(box.x, box.y, box.z, box.w, g0, g1, g2, g3);
            float iou = fmaxf(c, 0.f);
            if (iou <= 0.f) continue;                                  // align 0
            float pcv = pcls[nn];
            float ps = 1.f / (1.f + __expf(-pcv));
            float i2 = iou * iou;
            float a = ps * i2 * i2 * i2;                               // ps^1 * iou^6
            maxu = fmaxf(maxu, a);
            if (iou > 0.1f && a > tv[9]) {
                // strict > keeps earlier (lower n) ahead on ties == top_k stability
                tv[9] = a; ti[9] = n;
#pragma unroll
                for (int j = 9; j > 0; --j) {
                    if (tv[j] > tv[j - 1]) {
                        float tf = tv[j]; tv[j] = tv[j - 1]; tv[j - 1] = tf;
                        int   tt = ti[j]; ti[j] = ti[j - 1]; ti[j - 1] = tt;
                    }
                }
            }
        }
    }

    __shared__ float sval[2560];
    __shared__ int   sidx[2560];
    __shared__ float rv[256];
    __shared__ int   ra[256];
    __shared__ int   rs[256];
    __shared__ float smax[256];

#pragma unroll
    for (int j = 0; j < 10; j++) {
        sval[tid * 10 + j] = tv[j];
        sidx[tid * 10 + j] = ti[j];
    }
    smax[tid] = maxu;
    __syncthreads();
    for (int s = 128; s > 0; s >>= 1) {
        if (tid < s) smax[tid] = fmaxf(smax[tid], smax[tid + s]);
        __syncthreads();
    }
    float denom = smax[0] + 1e-9f;

    // 10 rounds of block argmax (value desc, anchor idx asc) over 2560 candidates
    for (int r = 0; r < 10; r++) {
        float bv = -1.f; int ba = 0x7fffffff; int bs = -1;
#pragma unroll
        for (int j = 0; j < 10; j++) {
            int s0 = tid * 10 + j;
            float v = sval[s0]; int a0 = sidx[s0];
            if (v > bv || (v == bv && a0 < ba)) { bv = v; ba = a0; bs = s0; }
        }
        rv[tid] = bv; ra[tid] = ba; rs[tid] = bs;
        __syncthreads();
        for (int s = 128; s > 0; s >>= 1) {
            if (tid < s) {
                if (rv[tid + s] > rv[tid] ||
                    (rv[tid + s] == rv[tid] && ra[tid + s] < ra[tid])) {
                    rv[tid] = rv[tid + s]; ra[tid] = ra[tid + s]; rs[tid] = rs[tid + s];
                }
            }
            __syncthreads();
        }
        if (tid == 0 && rv[0] > 0.f) {
            float nv = rv[0] / denom;                 // normalized score in (0, 1]
            unsigned long long pk =
                ((unsigned long long)__float_as_uint(nv) << 32) |
                (unsigned long long)(31 - m);         // ties -> lower m wins (argmax-first)
            atomicMax(&best[(size_t)b * NANCHOR + ra[0]], pk);
            sval[rs[0]] = -1.f;
        }
        __syncthreads();
    }
}

__global__ __launch_bounds__(256) void k_final(const float* __restrict__ p0,
                                               const float* __restrict__ p1,
                                               const float* __restrict__ p2,
                                               const float4* __restrict__ pb,
                                               const float* __restrict__ gtb,
                                               const int* __restrict__ gtl,
                                               const unsigned long long* __restrict__ best,
                                               float* __restrict__ acc) {
    int tid = blockIdx.x * blockDim.x + threadIdx.x;
    int b = tid / NANCHOR, n = tid % NANCHOR;
    unsigned long long pk = best[tid];
    unsigned int hi = (unsigned int)(pk >> 32);
    if (hi == 0u) return;                 // not foreground
    float score = __uint_as_float(hi);
    int m = 31 - (int)(pk & 0xffffffffull);
    const float* g = gtb + (size_t)(b * MGT + m) * 4;
    float g0 = g[0], g1 = g[1], g2 = g[2], g3 = g[3];
    int label = gtl[b * MGT + m];
    float4 box = pb[tid];
    float c = ciou_f(box.x, box.y, box.z, box.w, g0, g1, g2, g3);

    AInfo ai = anchor_info(p0, p1, p2, b, n);
    float inv_st = 1.f / ai.st;           // exact (power of two)
    float t4[4] = { ai.apx - g0 * inv_st, ai.apy - g1 * inv_st,
                    g2 * inv_st - ai.apx, g3 * inv_st - ai.apy };
    float dfl = 0.f;
#pragma unroll
    for (int k = 0; k < 4; k++) {
        float t = fminf(fmaxf(t4[k], 0.f), 14.99f);   // box2dist clamp
        int left = (int)floorf(t);
        int right = (left + 1 < 15) ? left + 1 : 15;
        float wl = (float)right - t;
        float wr = t - (float)left;
        float v[16];
        float mx = -1e30f;
#pragma unroll
        for (int r = 0; r < 16; r++) {
            v[r] = ai.ch0[(size_t)(k * 16 + r) * ai.hw];
            mx = fmaxf(mx, v[r]);
        }
        float s = 0.f;
#pragma unroll
        for (int r = 0; r < 16; r++) s += expf(v[r] - mx);
        float lse = mx + logf(s);
        dfl += (lse - v[left]) * wl + (lse - v[right]) * wr;
    }
    float pcv = ai.ch0[(size_t)(64 + label) * ai.hw];

    atomicAdd(&acc[b * 8 + 1], 1.f - c);       // box: (1 - ciou)
    atomicAdd(&acc[b * 8 + 2], dfl);           // dfl: sum over 4 sides
    atomicAdd(&acc[b * 8 + 3], pcv * score);   // cls positive term
    atomicAdd(&acc[b * 8 + 4], 1.f);           // num_fg
}

__global__ void k_combine(const float* __restrict__ acc, float* __restrict__ out) {
    if (blockIdx.x == 0 && threadIdx.x == 0) {
        float total = 0.f;
        for (int b = 0; b < BATCH; b++) {
            float nfr = acc[b * 8 + 4];
            float has = nfr > 0.f ? 1.f : 0.f;
            float nf = fmaxf(nfr, 1.f);
            float box_l = acc[b * 8 + 1] / nf;
            float cls_l = (acc[b * 8 + 0] - acc[b * 8 + 3]) / (float)NANCHOR;
            float dfl_l = acc[b * 8 + 2] / (nf * 4.f);
            total += has * (7.5f * box_l + 0.5f * cls_l + 1.5f * dfl_l);
        }
        out[0] = total;
    }
}

extern "C" void kernel_launch(void* const* d_in, const int* in_sizes, int n_in,
                              void* d_out, int out_size, void* d_ws, size_t ws_size,
                              hipStream_t stream) {
    (void)in_sizes; (void)n_in; (void)out_size; (void)ws_size;
    const float* p0  = (const float*)d_in[0];
    const float* p1  = (const float*)d_in[1];
    const float* p2  = (const float*)d_in[2];
    const float* gtb = (const float*)d_in[3];
    const int*   gtl = (const int*)d_in[4];
    // d_in[5] = strides (8,16,32) — hardcoded in anchor_info

    char* ws = (char*)d_ws;
    unsigned long long* best = (unsigned long long*)ws;                       // 2.15 MB
    float4* pb = (float4*)(ws + (size_t)BATCH * NANCHOR * 8);                 // 4.30 MB
    float*  acc = (float*)(ws + (size_t)BATCH * NANCHOR * 8
                              + (size_t)BATCH * NANCHOR * 16);                // 512 B

    const int BN = BATCH * NANCHOR;   // 268800
    k_init   <<<1, 128, 0, stream>>>(acc);
    k_decode <<<dim3(66, BATCH, 4), 128, 0, stream>>>(p0, p1, p2, (float2*)pb, best, acc);
    k_assign <<<BATCH * MGT, 256, 0, stream>>>(p0, p1, p2, pb, gtb, gtl, best);
    k_final  <<<BN / 256, 256, 0, stream>>>(p0, p1, p2, pb, gtb, gtl, best, acc);
    k_combine<<<1, 64, 0, stream>>>(acc, (float*)d_out);
}

// Round 5
// 263.040 us; speedup vs baseline: 1.4297x; 1.2122x over previous
//
#include <hip/hip_runtime.h>
#include <cstdint>

#define NANCHOR 33600
#define BATCH   8
#define MGT     32
#define NCLS    80
#define MAXFG   (BATCH * MGT * 10)   // 2560

// ---------------------------------------------------------------------------
// Anchor geometry: levels are [160x160 stride 8 | 80x80 stride 16 | 40x40 stride 32]
// p layout per level: [B, 144, H, W]; channel stride = H*W; anchor n = y*W + x.
// ---------------------------------------------------------------------------
struct AInfo {
    const float* ch0;   // &p_level[b][0][n]  (add c*hw for channel c)
    int   hw;
    float apx, apy, st;
};

__device__ __forceinline__ AInfo anchor_info(const float* p0, const float* p1,
                                             const float* p2, int b, int n) {
    AInfo r;
    if (n < 25600) {
        int nn = n;
        r.ch0 = p0 + (size_t)b * (144 * 25600) + nn;
        r.hw = 25600; r.st = 8.f;
        r.apx = (float)(nn % 160) + 0.5f;
        r.apy = (float)(nn / 160) + 0.5f;
    } else if (n < 32000) {
        int nn = n - 25600;
        r.ch0 = p1 + (size_t)b * (144 * 6400) + nn;
        r.hw = 6400; r.st = 16.f;
        r.apx = (float)(nn % 80) + 0.5f;
        r.apy = (float)(nn / 80) + 0.5f;
    } else {
        int nn = n - 32000;
        r.ch0 = p2 + (size_t)b * (144 * 1600) + nn;
        r.hw = 1600; r.st = 32.f;
        r.apx = (float)(nn % 40) + 0.5f;
        r.apy = (float)(nn / 40) + 0.5f;
    }
    return r;
}

__device__ __forceinline__ float ciou_f(float b1x1, float b1y1, float b1x2, float b1y2,
                                        float g1x, float g1y, float g2x, float g2y) {
    const float eps = 1e-7f;
    float w1 = b1x2 - b1x1, h1 = b1y2 - b1y1;
    float w2 = g2x - g1x,   h2 = g2y - g1y;
    float iw = fminf(b1x2, g2x) - fmaxf(b1x1, g1x);
    float ih = fminf(b1y2, g2y) - fmaxf(b1y1, g1y);
    float inter = fmaxf(iw, 0.f) * fmaxf(ih, 0.f);
    float uni = w1 * h1 + w2 * h2 - inter + eps;
    float iou = inter / uni;
    float cw = fmaxf(b1x2, g2x) - fminf(b1x1, g1x);
    float ch = fmaxf(b1y2, g2y) - fminf(b1y1, g1y);
    float c2 = cw * cw + ch * ch + eps;
    float dx = g1x + g2x - b1x1 - b1x2;
    float dy = g1y + g2y - b1y1 - b1y2;
    float rho2 = (dx * dx + dy * dy) * 0.25f;
    float t = atanf(w2 / (h2 + eps)) - atanf(w1 / (h1 + eps));
    float v = 0.40528473456935108577f * t * t;          // 4/pi^2
    float alpha = v / (v - iou + (1.f + eps));
    return iou - (rho2 / c2 + v * alpha);
}

__device__ __forceinline__ float4 max4(float4 a, float4 b) {
    return make_float4(fmaxf(a.x, b.x), fmaxf(a.y, b.y), fmaxf(a.z, b.z), fmaxf(a.w, b.w));
}
__device__ __forceinline__ float fast_splus(float x) {
    // softplus = max(x,0) + log(1 + e^{-|x|}) via native v_exp/v_log
    return fmaxf(x, 0.f) + __logf(1.f + __expf(-fabsf(x)));
}

// ---------------------------------------------------------------------------
// ws layout:
//   best : unsigned long long [B*N]   packed (score_bits<<32)|(31-m); 0 == no fg
//   pb   : float4 [B*N]               decoded pred boxes (image units, xyxy)
//   acc  : float [128]   per image b: [b*8+0]=softplus_sum, +1=box, +2=dfl,
//                        +3=clspos, +4=numfg;  ((uint*)acc)[120] = fg-list count
//   fglist : uint2 [MAXFG]            (bn = b*NANCHOR+n, m)
// ---------------------------------------------------------------------------

__global__ void k_init(float* acc) {
    acc[threadIdx.x] = 0.f;     // 128 threads clear 128 floats (incl. list counter)
}

// grid (66, BATCH, 4), block 128. One thread = 4 consecutive anchors.
// role 0: DFL sides 0,1 -> writes {x1,y1} float2 halves of pb, clears best
// role 1: DFL sides 2,3 -> writes {x2,y2}
// role 2: softplus channels 64..103 ; role 3: channels 104..143
__global__ __launch_bounds__(128) void k_decode(const float* __restrict__ p0,
                                                const float* __restrict__ p1,
                                                const float* __restrict__ p2,
                                                float2* __restrict__ pb2,
                                                unsigned long long* __restrict__ best,
                                                float* __restrict__ acc) {
    int b = blockIdx.y;
    int role = blockIdx.z;
    int t = blockIdx.x * 128 + threadIdx.x;   // anchor-group index in image

    if (role >= 2) {
        float sp = 0.f;
        if (t < NANCHOR / 4) {
            int n = t * 4;
            const float* ch0; int hw;
            if (n < 25600)      { ch0 = p0 + (size_t)b * (144 * 25600) + n;          hw = 25600; }
            else if (n < 32000) { ch0 = p1 + (size_t)b * (144 * 6400) + (n - 25600); hw = 6400; }
            else                { ch0 = p2 + (size_t)b * (144 * 1600) + (n - 32000); hw = 1600; }
            int c0 = 64 + (role - 2) * 40;
#pragma unroll 8
            for (int c = 0; c < 40; c++) {
                float4 x = *(const float4*)(ch0 + (size_t)(c0 + c) * hw);
                sp += fast_splus(x.x) + fast_splus(x.y) + fast_splus(x.z) + fast_splus(x.w);
            }
        }
#pragma unroll
        for (int o = 32; o > 0; o >>= 1) sp += __shfl_down(sp, o, 64);
        if ((threadIdx.x & 63) == 0) atomicAdd(&acc[b * 8 + 0], sp);
        return;
    }

    if (t >= NANCHOR / 4) return;
    int n = t * 4;
    const float* ch0; int hw; float st, apx, apy;
    if (n < 25600) {
        ch0 = p0 + (size_t)b * (144 * 25600) + n;
        hw = 25600; st = 8.f;
        apx = (float)(n % 160) + 0.5f; apy = (float)(n / 160) + 0.5f;
    } else if (n < 32000) {
        int nn = n - 25600;
        ch0 = p1 + (size_t)b * (144 * 6400) + nn;
        hw = 6400; st = 16.f;
        apx = (float)(nn % 80) + 0.5f; apy = (float)(nn / 80) + 0.5f;
    } else {
        int nn = n - 32000;
        ch0 = p2 + (size_t)b * (144 * 1600) + nn;
        hw = 1600; st = 32.f;
        apx = (float)(nn % 40) + 0.5f; apy = (float)(nn / 40) + 0.5f;
    }

    int k0 = role * 2;                  // sides {0,1} or {2,3}
    float d[2][4];
#pragma unroll
    for (int kk = 0; kk < 2; kk++) {
        float4 v[16];
#pragma unroll
        for (int r = 0; r < 16; r++)
            v[r] = *(const float4*)(ch0 + (size_t)((k0 + kk) * 16 + r) * hw);
        float4 mx = v[0];
#pragma unroll
        for (int r = 1; r < 16; r++) mx = max4(mx, v[r]);
        float4 s  = make_float4(0.f, 0.f, 0.f, 0.f);
        float4 sw = make_float4(0.f, 0.f, 0.f, 0.f);
#pragma unroll
        for (int r = 0; r < 16; r++) {
            float fr = (float)r;
            float ex = __expf(v[r].x - mx.x);
            float ey = __expf(v[r].y - mx.y);
            float ez = __expf(v[r].z - mx.z);
            float ew = __expf(v[r].w - mx.w);
            s.x += ex; s.y += ey; s.z += ez; s.w += ew;
            sw.x += ex * fr; sw.y += ey * fr; sw.z += ez * fr; sw.w += ew * fr;
        }
        d[kk][0] = sw.x / s.x; d[kk][1] = sw.y / s.y;
        d[kk][2] = sw.z / s.z; d[kk][3] = sw.w / s.w;
    }

    size_t base = (size_t)b * NANCHOR + n;
    if (role == 0) {
#pragma unroll
        for (int i = 0; i < 4; i++) {
            float ax = apx + (float)i;
            pb2[(base + i) * 2 + 0] = make_float2((ax - d[0][i]) * st, (apy - d[1][i]) * st);
        }
        // clear fg table for k_assign (runs strictly after this kernel)
#pragma unroll
        for (int i = 0; i < 4; i++) best[base + i] = 0ull;
    } else {
#pragma unroll
        for (int i = 0; i < 4; i++) {
            float ax = apx + (float)i;
            pb2[(base + i) * 2 + 1] = make_float2((ax + d[0][i]) * st, (apy + d[1][i]) * st);
        }
    }
}

// One block per (b, m). Scans only the per-level index window covering the GT
// box (conservative ±1; exact float in-gt test inside). Selection semantics
// are order-independent: (align value desc, anchor index asc).
// Selected anchors are appended to the compact fg list for k_final.
__global__ __launch_bounds__(256) void k_assign(const float* __restrict__ p0,
                                                const float* __restrict__ p1,
                                                const float* __restrict__ p2,
                                                const float4* __restrict__ pb,
                                                const float* __restrict__ gtb,
                                                const int* __restrict__ gtl,
                                                unsigned long long* __restrict__ best,
                                                float* __restrict__ acc,
                                                uint2* __restrict__ fglist) {
    int bm = blockIdx.x;          // 256 blocks: one per (b, m)
    int b = bm >> 5, m = bm & 31;
    const float* g = gtb + (size_t)(b * MGT + m) * 4;
    float g0 = g[0], g1 = g[1], g2 = g[2], g3 = g[3];
    int label = gtl[b * MGT + m];
    int tid = threadIdx.x;

    float tv[10];
    int   ti[10];
#pragma unroll
    for (int j = 0; j < 10; j++) { tv[j] = -1.f; ti[j] = 0x7fffffff; }
    float maxu = 0.f;   // max over UNMASKED align (pre iou>0.1 filter)

    const int   LW[3]   = {160, 80, 40};
    const int   LOFF[3] = {0, 25600, 32000};
    const float LST[3]  = {8.f, 16.f, 32.f};

    for (int l = 0; l < 3; l++) {
        float st = LST[l];
        int W = LW[l];
        float inv_st = 1.f / st;
        int ix0 = max(0,     (int)floorf(g0 * inv_st - 0.5f) - 1);
        int ix1 = min(W - 1, (int)ceilf (g2 * inv_st - 0.5f) + 1);
        int iy0 = max(0,     (int)floorf(g1 * inv_st - 0.5f) - 1);
        int iy1 = min(W - 1, (int)ceilf (g3 * inv_st - 0.5f) + 1);
        int nx = ix1 - ix0 + 1, ny = iy1 - iy0 + 1;
        if (nx <= 0 || ny <= 0) continue;
        int cnt = nx * ny;
        const float* lp = (l == 0) ? p0 : (l == 1) ? p1 : p2;
        int hw = W * W;
        const float* ch0 = lp + (size_t)b * 144 * hw;
        const float* pcls = ch0 + (size_t)(64 + label) * hw;

        for (int idx = tid; idx < cnt; idx += 256) {
            int iy = iy0 + idx / nx;
            int ix = ix0 + idx % nx;
            float ax = ((float)ix + 0.5f) * st;
            float ay = ((float)iy + 0.5f) * st;
            if (ax < g0 || ax > g2 || ay < g1 || ay > g3) continue;   // exact in_gt
            int nn = iy * W + ix;
            int n = LOFF[l] + nn;
            float4 box = pb[(size_t)b * NANCHOR + n];
            float c = ciou_f(box.x, box.y, box.z, box.w, g0, g1, g2, g3);
            float iou = fmaxf(c, 0.f);
            if (iou <= 0.f) continue;                                  // align 0
            float pcv = pcls[nn];
            float ps = 1.f / (1.f + __expf(-pcv));
            float i2 = iou * iou;
            float a = ps * i2 * i2 * i2;                               // ps^1 * iou^6
            maxu = fmaxf(maxu, a);
            if (iou > 0.1f && a > tv[9]) {
                // strict > keeps earlier (lower n) ahead on ties == top_k stability
                tv[9] = a; ti[9] = n;
#pragma unroll
                for (int j = 9; j > 0; --j) {
                    if (tv[j] > tv[j - 1]) {
                        float tf = tv[j]; tv[j] = tv[j - 1]; tv[j - 1] = tf;
                        int   tt = ti[j]; ti[j] = ti[j - 1]; ti[j - 1] = tt;
                    }
                }
            }
        }
    }

    __shared__ float sval[2560];
    __shared__ int   sidx[2560];
    __shared__ float rv[256];
    __shared__ int   ra[256];
    __shared__ int   rs[256];
    __shared__ float smax[256];
    __shared__ int   winners[10];
    __shared__ int   nwin;

#pragma unroll
    for (int j = 0; j < 10; j++) {
        sval[tid * 10 + j] = tv[j];
        sidx[tid * 10 + j] = ti[j];
    }
    smax[tid] = maxu;
    if (tid == 0) nwin = 0;
    __syncthreads();
    for (int s = 128; s > 0; s >>= 1) {
        if (tid < s) smax[tid] = fmaxf(smax[tid], smax[tid + s]);
        __syncthreads();
    }
    float denom = smax[0] + 1e-9f;

    // 10 rounds of block argmax (value desc, anchor idx asc) over 2560 candidates
    for (int r = 0; r < 10; r++) {
        float bv = -1.f; int ba = 0x7fffffff; int bs = -1;
#pragma unroll
        for (int j = 0; j < 10; j++) {
            int s0 = tid * 10 + j;
            float v = sval[s0]; int a0 = sidx[s0];
            if (v > bv || (v == bv && a0 < ba)) { bv = v; ba = a0; bs = s0; }
        }
        rv[tid] = bv; ra[tid] = ba; rs[tid] = bs;
        __syncthreads();
        for (int s = 128; s > 0; s >>= 1) {
            if (tid < s) {
                if (rv[tid + s] > rv[tid] ||
                    (rv[tid + s] == rv[tid] && ra[tid + s] < ra[tid])) {
                    rv[tid] = rv[tid + s]; ra[tid] = ra[tid + s]; rs[tid] = rs[tid + s];
                }
            }
            __syncthreads();
        }
        if (tid == 0 && rv[0] > 0.f) {
            float nv = rv[0] / denom;                 // normalized score in (0, 1]
            unsigned long long pk =
                ((unsigned long long)__float_as_uint(nv) << 32) |
                (unsigned long long)(31 - m);         // ties -> lower m wins (argmax-first)
            atomicMax(&best[(size_t)b * NANCHOR + ra[0]], pk);
            winners[nwin++] = ra[0];
            sval[rs[0]] = -1.f;
        }
        __syncthreads();
    }

    if (tid == 0 && nwin > 0) {
        unsigned int* list_cnt = (unsigned int*)(acc + 120);
        unsigned int base = atomicAdd(list_cnt, (unsigned int)nwin);
        for (int j = 0; j < nwin; j++)
            fglist[base + j] = make_uint2((unsigned int)(b * NANCHOR + winners[j]),
                                          (unsigned int)m);
    }
}

// Dense pass over the compact fg list. Entry processed only if its GT won the
// per-anchor argmax (best[bn] low bits == 31-m) -> exact dedupe semantics.
__global__ __launch_bounds__(256) void k_final(const float* __restrict__ p0,
                                               const float* __restrict__ p1,
                                               const float* __restrict__ p2,
                                               const float4* __restrict__ pb,
                                               const float* __restrict__ gtb,
                                               const int* __restrict__ gtl,
                                               const unsigned long long* __restrict__ best,
                                               const uint2* __restrict__ fglist,
                                               float* __restrict__ acc) {
    __shared__ float sacc[BATCH][4];   // {box, dfl, clspos, numfg}
    int tid = threadIdx.x;
    if (tid < BATCH * 4) sacc[tid >> 2][tid & 3] = 0.f;
    __syncthreads();

    unsigned int cnt = *(const unsigned int*)(acc + 120);
    unsigned int i = blockIdx.x * 256 + tid;
    if (i < cnt) {
        uint2 e = fglist[i];
        int bn = (int)e.x, m = (int)e.y;
        unsigned long long pk = best[bn];
        if ((unsigned int)(pk & 0xffffffffull) == (unsigned int)(31 - m)) {
            int b = bn / NANCHOR, n = bn % NANCHOR;
            float score = __uint_as_float((unsigned int)(pk >> 32));
            const float* g = gtb + (size_t)(b * MGT + m) * 4;
            float g0 = g[0], g1 = g[1], g2 = g[2], g3 = g[3];
            int label = gtl[b * MGT + m];
            float4 box = pb[bn];
            float c = ciou_f(box.x, box.y, box.z, box.w, g0, g1, g2, g3);

            AInfo ai = anchor_info(p0, p1, p2, b, n);
            float inv_st = 1.f / ai.st;           // exact (power of two)
            float t4[4] = { ai.apx - g0 * inv_st, ai.apy - g1 * inv_st,
                            g2 * inv_st - ai.apx, g3 * inv_st - ai.apy };
            float dfl = 0.f;
#pragma unroll
            for (int k = 0; k < 4; k++) {
                float t = fminf(fmaxf(t4[k], 0.f), 14.99f);   // box2dist clamp
                int left = (int)floorf(t);
                int right = (left + 1 < 15) ? left + 1 : 15;
                float wl = (float)right - t;
                float wr = t - (float)left;
                float v[16];
                float mx = -1e30f;
#pragma unroll
                for (int r = 0; r < 16; r++) {
                    v[r] = ai.ch0[(size_t)(k * 16 + r) * ai.hw];
                    mx = fmaxf(mx, v[r]);
                }
                float s = 0.f;
#pragma unroll
                for (int r = 0; r < 16; r++) s += __expf(v[r] - mx);
                float lse = mx + __logf(s);
                dfl += (lse - v[left]) * wl + (lse - v[right]) * wr;
            }
            float pcv = ai.ch0[(size_t)(64 + label) * ai.hw];

            atomicAdd(&sacc[b][0], 1.f - c);
            atomicAdd(&sacc[b][1], dfl);
            atomicAdd(&sacc[b][2], pcv * score);
            atomicAdd(&sacc[b][3], 1.f);
        }
    }
    __syncthreads();
    if (tid < BATCH * 4) {
        float v = sacc[tid >> 2][tid & 3];
        if (v != 0.f) atomicAdd(&acc[(tid >> 2) * 8 + 1 + (tid & 3)], v);
    }
}

__global__ void k_combine(const float* __restrict__ acc, float* __restrict__ out) {
    if (blockIdx.x == 0 && threadIdx.x == 0) {
        float total = 0.f;
        for (int b = 0; b < BATCH; b++) {
            float nfr = acc[b * 8 + 4];
            float has = nfr > 0.f ? 1.f : 0.f;
            float nf = fmaxf(nfr, 1.f);
            float box_l = acc[b * 8 + 1] / nf;
            float cls_l = (acc[b * 8 + 0] - acc[b * 8 + 3]) / (float)NANCHOR;
            float dfl_l = acc[b * 8 + 2] / (nf * 4.f);
            total += has * (7.5f * box_l + 0.5f * cls_l + 1.5f * dfl_l);
        }
        out[0] = total;
    }
}

extern "C" void kernel_launch(void* const* d_in, const int* in_sizes, int n_in,
                              void* d_out, int out_size, void* d_ws, size_t ws_size,
                              hipStream_t stream) {
    (void)in_sizes; (void)n_in; (void)out_size; (void)ws_size;
    const float* p0  = (const float*)d_in[0];
    const float* p1  = (const float*)d_in[1];
    const float* p2  = (const float*)d_in[2];
    const float* gtb = (const float*)d_in[3];
    const int*   gtl = (const int*)d_in[4];
    // d_in[5] = strides (8,16,32) — hardcoded in anchor_info

    char* ws = (char*)d_ws;
    unsigned long long* best = (unsigned long long*)ws;                       // 2.15 MB
    float4* pb = (float4*)(ws + (size_t)BATCH * NANCHOR * 8);                 // 4.30 MB
    float*  acc = (float*)(ws + (size_t)BATCH * NANCHOR * 8
                              + (size_t)BATCH * NANCHOR * 16);                // 512 B
    uint2* fglist = (uint2*)((char*)acc + 512);                               // 20 KB

    k_init   <<<1, 128, 0, stream>>>(acc);
    k_decode <<<dim3(66, BATCH, 4), 128, 0, stream>>>(p0, p1, p2, (float2*)pb, best, acc);
    k_assign <<<BATCH * MGT, 256, 0, stream>>>(p0, p1, p2, pb, gtb, gtl, best, acc, fglist);
    k_final  <<<(MAXFG + 255) / 256, 256, 0, stream>>>(p0, p1, p2, pb, gtb, gtl, best,
                                                       fglist, acc);
    k_combine<<<1, 64, 0, stream>>>(acc, (float*)d_out);
}